// Round 6
// baseline (470.384 us; speedup 1.0000x reference)
//
#include <hip/hip_runtime.h>

// OnlineEmbedding: out[b,h,:] = table[ids[b,h], :]
// ids: [4096*200] int32 (values < 1e6), table: [1e6, 64] fp32, out: [4096*200, 64] fp32.
//
// R6 = R5 resubmit (acquisition timeout; probe never ran).
// R5 = MEASUREMENT PROBE. R4 landed at 392.25us vs 392.1 baseline (+0.04%)
// despite 4x MLP + nt-stores => measured time is NOT kernel-dominated.
// Evidence: rocprof top-5 by duration shows only 1GB fillBufferAligned
// dispatches at ~157-160us (harness re-poison, ~6.4TB/s = incompressible);
// our gather never appears => gather per-dispatch < 157us, so dur_us=392
// includes ~316us of harness fills. Probe: launch the IDENTICAL gather twice
// (idempotent: same bytes written twice, serialized on one stream -> correct).
// delta(dur_us) = one warm gather pass T2.
//   T2 ~70-90us  -> kernel at random-access roofline; declare ROOFLINE next.
//   T2 <=50us    -> L3-warm gather fast; headroom <= ~40us, reassess.
//   T2 >=120us   -> fixed floor smaller than assumed; locality work has ~2x room.

typedef float f32x4 __attribute__((ext_vector_type(4)));

#define UNROLL 4

__global__ __launch_bounds__(256) void OnlineEmbedding_gather(
    const int* __restrict__ ids,
    const f32x4* __restrict__ table,
    f32x4* __restrict__ out,
    int n_ids)
{
    const int c = threadIdx.x & 15;          // which 16B chunk of the 256B row
    const int g = threadIdx.x >> 4;          // row-group within block: 0..15
    const int row0 = blockIdx.x * (16 * UNROLL) + g;

    int id[UNROLL];
#pragma unroll
    for (int k = 0; k < UNROLL; ++k) {
        int r = row0 + 16 * k;
        id[k] = (r < n_ids) ? __builtin_nontemporal_load(&ids[r]) : 0;
    }

    f32x4 v[UNROLL];
#pragma unroll
    for (int k = 0; k < UNROLL; ++k) {
        v[k] = table[(size_t)id[k] * 16 + c];
    }

#pragma unroll
    for (int k = 0; k < UNROLL; ++k) {
        int r = row0 + 16 * k;
        if (r < n_ids) {
            __builtin_nontemporal_store(v[k], &out[(size_t)r * 16 + c]);
        }
    }
}

extern "C" void kernel_launch(void* const* d_in, const int* in_sizes, int n_in,
                              void* d_out, int out_size, void* d_ws, size_t ws_size,
                              hipStream_t stream) {
    const int*   ids   = (const int*)d_in[0];
    const f32x4* table = (const f32x4*)d_in[1];
    f32x4*       out   = (f32x4*)d_out;

    int n_ids = in_sizes[0];                       // 4096*200 = 819200
    int rows_per_block = 16 * UNROLL;              // 64
    int block = 256;
    int grid  = (n_ids + rows_per_block - 1) / rows_per_block;  // 12800

    // Launch 1: the real work.
    OnlineEmbedding_gather<<<grid, block, 0, stream>>>(ids, table, out, n_ids);
    // Launch 2: PROBE — identical, idempotent, serialized on the same stream.
    // dur_us delta vs R4 (392.25us) == duration of one warm gather pass.
    OnlineEmbedding_gather<<<grid, block, 0, stream>>>(ids, table, out, n_ids);
}

// Round 7
// 391.572 us; speedup vs baseline: 1.2013x; 1.2013x over previous
//
#include <hip/hip_runtime.h>

// OnlineEmbedding: out[b,h,:] = table[ids[b,h], :]
// ids: [4096*200] int32 (values < 1e6), table: [1e6, 64] fp32, out: [4096*200, 64] fp32.
//
// R7 = revert to the single-launch R4 kernel (best measured: 392.25us).
//
// MEASUREMENT CONCLUSION (R4 + R6 probe):
//   - Timed region = 2x 1.024GB harness fillBufferAligned (~316-356us,
//     incompressible, runs at achievable HBM peak) + ONE gather pass.
//   - Gather pass = 57-78us (R6 double-launch delta / per-run decomposition).
//   - Gather roofline: 3.3MB ids + ~143MB distinct random 256B rows
//     + 210MB streaming writes ~= 356MB => >=56.5us @ 6.3TB/s. Kernel is at
//     1.0-1.4x its memory bound; headroom <=5% of the metric, below
//     measurement noise of the fill floor.
//
// Kernel structure (R4):
//   - 16 consecutive lanes per embedding row (lane c -> c-th float4): each
//     wave load/store touches 4 consecutive rows = 1KB contiguous.
//   - UNROLL=4 independent gathers per thread: 16 random 256B segments in
//     flight per wave.
//   - nt stores for write-once output, nt loads for read-once ids; table
//     reads cached normally (L2/L3-resident by reuse).

typedef float f32x4 __attribute__((ext_vector_type(4)));

#define UNROLL 4

__global__ __launch_bounds__(256) void OnlineEmbedding_gather(
    const int* __restrict__ ids,
    const f32x4* __restrict__ table,
    f32x4* __restrict__ out,
    int n_ids)
{
    const int c = threadIdx.x & 15;          // which 16B chunk of the 256B row
    const int g = threadIdx.x >> 4;          // row-group within block: 0..15
    const int row0 = blockIdx.x * (16 * UNROLL) + g;

    int id[UNROLL];
#pragma unroll
    for (int k = 0; k < UNROLL; ++k) {
        int r = row0 + 16 * k;
        id[k] = (r < n_ids) ? __builtin_nontemporal_load(&ids[r]) : 0;
    }

    f32x4 v[UNROLL];
#pragma unroll
    for (int k = 0; k < UNROLL; ++k) {
        v[k] = table[(size_t)id[k] * 16 + c];
    }

#pragma unroll
    for (int k = 0; k < UNROLL; ++k) {
        int r = row0 + 16 * k;
        if (r < n_ids) {
            __builtin_nontemporal_store(v[k], &out[(size_t)r * 16 + c]);
        }
    }
}

extern "C" void kernel_launch(void* const* d_in, const int* in_sizes, int n_in,
                              void* d_out, int out_size, void* d_ws, size_t ws_size,
                              hipStream_t stream) {
    const int*   ids   = (const int*)d_in[0];
    const f32x4* table = (const f32x4*)d_in[1];
    f32x4*       out   = (f32x4*)d_out;

    int n_ids = in_sizes[0];                       // 4096*200 = 819200
    int rows_per_block = 16 * UNROLL;              // 64
    int block = 256;
    int grid  = (n_ids + rows_per_block - 1) / rows_per_block;  // 12800

    OnlineEmbedding_gather<<<grid, block, 0, stream>>>(ids, table, out, n_ids);
}